// Round 5
// baseline (239.444 us; speedup 1.0000x reference)
//
#include <hip/hip_runtime.h>
#include <hip/hip_bf16.h>

// Conv_SelfAttn — B=8, C=128, N=4096, C_QK=16. fp32 in/out.
// Round 5: attn restructure for occupancy.
//  - 512 threads / 8 waves: waves 0-3 keys [0,2048), waves 4-7 [2048,4096),
//    same 128 queries; exact fp32 (m,l,O) merge via LDS at the end.
//  - K frags direct from global (no kT LDS); P^T frags via shfl_xor(32)
//    (no Pl LDS); vT double-buffered ping-pong -> 1 barrier/iter.
// Layouts (32x32x16_bf16), all verified by round-4 absmax 0.031:
//   C/D: col=lane&31, row=(reg&3)+8*(reg>>2)+4*(lane>>5)
//   A  : m=lane&31,  k=8*(lane>>5)+j
//   B  : n=lane&31,  k=8*(lane>>5)+j
// ws: qw fp32 [B][N][16] | kw fp32 [B][N][16] | vw bf16 [B][C][N] (V^T)

typedef __bf16 bf16x8 __attribute__((ext_vector_type(8)));
typedef __bf16 bf16x4 __attribute__((ext_vector_type(4)));
typedef float  f32x16 __attribute__((ext_vector_type(16)));
typedef unsigned int u32;
typedef u32 u32x4 __attribute__((ext_vector_type(4)));

static constexpr int Bb = 8, Cc = 128, Nn = 4096, CQ = 16;

__device__ __forceinline__ f32x16 mfma32(bf16x8 a, bf16x8 b, f32x16 c) {
    return __builtin_amdgcn_mfma_f32_32x32x16_bf16(a, b, c, 0, 0, 0);
}
struct HL { __bf16 h, l; };
__device__ __forceinline__ HL hilo(float f) {
    HL r;
    r.h = (__bf16)f;
    r.l = (__bf16)(f - (float)r.h);
    return r;
}
__device__ __forceinline__ u32 pack2(float a, float b) {
    unsigned short ua = __builtin_bit_cast(unsigned short, (__bf16)a);
    unsigned short ub = __builtin_bit_cast(unsigned short, (__bf16)b);
    return (u32)ua | ((u32)ub << 16);
}

// ---------------- Kernel 1: QKV projection (MFMA) — unchanged ----------------
__global__ __launch_bounds__(256) void qkv_kernel(
    const float* __restrict__ x, const float* __restrict__ Wq,
    const float* __restrict__ Wk, const float* __restrict__ Wv,
    float* __restrict__ qw, float* __restrict__ kw, __bf16* __restrict__ vw)
{
    const int b = blockIdx.y, n0 = blockIdx.x * 64, t = threadIdx.x;
    const int wave = t >> 6, lane = t & 63, lr = lane & 31, lq = lane >> 5;

    __shared__ __bf16 xh[64][136], xl[64][136];
    __shared__ __bf16 wqh[32][136], wql[32][136];
    __shared__ __bf16 wvh[128][136];

    {
        const int n = t & 63, cib = t >> 6;
        #pragma unroll 4
        for (int i = 0; i < 32; ++i) {
            int ci = cib + i * 4;
            float v = x[((size_t)(b * Cc + ci)) * Nn + n0 + n];
            HL z = hilo(v);
            xh[n][ci] = z.h; xl[n][ci] = z.l;
        }
    }
    #pragma unroll
    for (int i = 0; i < 8; ++i) {
        int idx = t + i * 256;
        int o = idx >> 7, ci = idx & 127;
        HL zq = hilo(Wq[idx]);
        wqh[o][ci] = zq.h; wql[o][ci] = zq.l;
        HL zk = hilo(Wk[idx]);
        wqh[16 + o][ci] = zk.h; wql[16 + o][ci] = zk.l;
    }
    #pragma unroll
    for (int i = 0; i < 16; ++i) {
        int flat = t * 4 + i * 1024;
        float4 w4 = *(const float4*)(Wv + flat);
        int c = flat >> 7, ci0 = flat & 127;
        bf16x4 h4 = { (__bf16)w4.x, (__bf16)w4.y, (__bf16)w4.z, (__bf16)w4.w };
        *(bf16x4*)&wvh[c][ci0] = h4;
    }
    __syncthreads();

    if (wave < 2) {
        const int nh = wave;
        f32x16 acc = {};
        #pragma unroll
        for (int ks = 0; ks < 8; ++ks) {
            bf16x8 ah = *(const bf16x8*)&wqh[lr][ks * 16 + lq * 8];
            bf16x8 al = *(const bf16x8*)&wql[lr][ks * 16 + lq * 8];
            bf16x8 bh = *(const bf16x8*)&xh[nh * 32 + lr][ks * 16 + lq * 8];
            bf16x8 bl = *(const bf16x8*)&xl[nh * 32 + lr][ks * 16 + lq * 8];
            acc = mfma32(ah, bh, acc);
            acc = mfma32(al, bh, acc);
            acc = mfma32(ah, bl, acc);
        }
        const int n = n0 + nh * 32 + lr;
        #pragma unroll
        for (int r = 0; r < 16; ++r) {
            int op = (r & 3) + 8 * (r >> 2) + 4 * lq;
            if (op < 16) qw[((size_t)(b * Nn + n)) * CQ + op] = acc[r];
            else         kw[((size_t)(b * Nn + n)) * CQ + (op - 16)] = acc[r];
        }
    }
    {
        int tl[3][2]; int nt;
        if      (wave == 0) { tl[0][0]=2; tl[0][1]=0; nt=1; }
        else if (wave == 1) { tl[0][0]=2; tl[0][1]=1; nt=1; }
        else if (wave == 2) { tl[0][0]=0; tl[0][1]=0; tl[1][0]=1; tl[1][1]=0; tl[2][0]=3; tl[2][1]=0; nt=3; }
        else                { tl[0][0]=0; tl[0][1]=1; tl[1][0]=1; tl[1][1]=1; tl[2][0]=3; tl[2][1]=1; nt=3; }
        for (int ti = 0; ti < nt; ++ti) {
            const int ct = tl[ti][0], nh = tl[ti][1];
            f32x16 acc = {};
            #pragma unroll
            for (int ks = 0; ks < 8; ++ks) {
                bf16x8 a  = *(const bf16x8*)&wvh[ct * 32 + lr][ks * 16 + lq * 8];
                bf16x8 bh = *(const bf16x8*)&xh[nh * 32 + lr][ks * 16 + lq * 8];
                acc = mfma32(a, bh, acc);
            }
            const int n = n0 + nh * 32 + lr;
            #pragma unroll
            for (int r = 0; r < 16; ++r) {
                int c = (r & 3) + 8 * (r >> 2) + 4 * lq + ct * 32;
                vw[((size_t)(b * Cc + c)) * Nn + n] = (__bf16)acc[r];
            }
        }
    }
}

// ---------------- Kernel 2: MFMA flash attention, 8 waves, key-split ----------
// grid (32, 8), 512 threads.
__global__ __launch_bounds__(512) void attn_kernel(
    const float* __restrict__ x, const float* __restrict__ qw,
    const float* __restrict__ kw, const __bf16* __restrict__ vw,
    const float* __restrict__ gamma, float* __restrict__ out)
{
    const int b = blockIdx.y, n0b = blockIdx.x * 128, t = threadIdx.x;
    const int wave = t >> 6, lane = t & 63, lr = lane & 31, lq = lane >> 5;
    const int qg = wave & 3, half = wave >> 2;
    const int kbase = half * 2048;

    __shared__ __bf16 vT[2][2][128][72];   // [half][buf][c][m], 73728 B

    // V staging: 256 threads per half; thread u: c = u>>1, m-seg (u&1)*32
    const int u = t & 255;
    const int sc = u >> 1, sm = (u & 1) * 32;

    auto loadV = [&](int chunk, uint4* r) {
        const __bf16* base = vw + ((size_t)(b * Cc + sc)) * Nn + kbase + chunk * 64 + sm;
        #pragma unroll
        for (int i = 0; i < 4; ++i) r[i] = *(const uint4*)(base + 8 * i);
    };
    auto storeV = [&](int buf, const uint4* r) {
        #pragma unroll
        for (int i = 0; i < 4; ++i) *(uint4*)&vT[half][buf][sc][sm + 8 * i] = r[i];
    };

    // Q frags (global, once)
    const int nq = n0b + qg * 32 + lr;
    bf16x8 qhi, qlo;
    {
        float qa[8];
        *(float4*)&qa[0] = *(const float4*)(qw + ((size_t)b * Nn + nq) * CQ + lq * 8);
        *(float4*)&qa[4] = *(const float4*)(qw + ((size_t)b * Nn + nq) * CQ + lq * 8 + 4);
        #pragma unroll
        for (int j = 0; j < 8; ++j) { HL z = hilo(qa[j]); qhi[j] = z.h; qlo[j] = z.l; }
    }

    uint4 vr[4];
    loadV(0, vr); storeV(0, vr);
    loadV(1, vr);
    __syncthreads();

    f32x16 acc[4] = {{}, {}, {}, {}};
    float m_run = -3e38f, l_run = 0.f;

    for (int it = 0; it < 32; ++it) {
        const int p = it & 1;

        // K frags for this 64-key chunk (fp32 global -> hi/lo regs)
        const size_t krow = (size_t)b * Nn + kbase + it * 64;
        bf16x8 k0h, k0l, k1h, k1l;
        {
            float ka[8], kb[8];
            *(float4*)&ka[0] = *(const float4*)(kw + (krow + lr) * CQ + lq * 8);
            *(float4*)&ka[4] = *(const float4*)(kw + (krow + lr) * CQ + lq * 8 + 4);
            *(float4*)&kb[0] = *(const float4*)(kw + (krow + 32 + lr) * CQ + lq * 8);
            *(float4*)&kb[4] = *(const float4*)(kw + (krow + 32 + lr) * CQ + lq * 8 + 4);
            #pragma unroll
            for (int j = 0; j < 8; ++j) {
                HL z = hilo(ka[j]); k0h[j] = z.h; k0l[j] = z.l;
                HL w = hilo(kb[j]); k1h[j] = w.h; k1l[j] = w.l;
            }
        }

        // S^T = K * Q^T (rows = keys, cols = queries)
        f32x16 s0 = {}, s1 = {};
        s0 = mfma32(k0h, qhi, s0); s0 = mfma32(k0l, qhi, s0); s0 = mfma32(k0h, qlo, s0);
        s1 = mfma32(k1h, qhi, s1); s1 = mfma32(k1l, qhi, s1); s1 = mfma32(k1h, qlo, s1);

        // online softmax for query lr (lane pair via xor-32)
        float cmax = -3e38f;
        #pragma unroll
        for (int r = 0; r < 16; ++r) { cmax = fmaxf(cmax, s0[r]); cmax = fmaxf(cmax, s1[r]); }
        cmax = fmaxf(cmax, __shfl_xor(cmax, 32));
        const float mnew = fmaxf(m_run, cmax);
        const float alpha = __expf(m_run - mnew);
        float p0[16], p1[16], csum = 0.f;
        #pragma unroll
        for (int r = 0; r < 16; ++r) {
            p0[r] = __expf(s0[r] - mnew); csum += p0[r];
            p1[r] = __expf(s1[r] - mnew); csum += p1[r];
        }
        csum += __shfl_xor(csum, 32);
        l_run = l_run * alpha + csum;
        m_run = mnew;
        #pragma unroll
        for (int ct = 0; ct < 4; ++ct)
            #pragma unroll
            for (int r = 0; r < 16; ++r) acc[ct][r] *= alpha;

        // pack P to bf16 pairs; exchange quads with xor-32 partner
        u32 Qk[16], Sh[16];
        #pragma unroll
        for (int g = 0; g < 4; ++g) {
            Qk[g * 2]     = pack2(p0[4 * g],     p0[4 * g + 1]);
            Qk[g * 2 + 1] = pack2(p0[4 * g + 2], p0[4 * g + 3]);
            Qk[8 + g * 2]     = pack2(p1[4 * g],     p1[4 * g + 1]);
            Qk[8 + g * 2 + 1] = pack2(p1[4 * g + 2], p1[4 * g + 3]);
        }
        #pragma unroll
        for (int i = 0; i < 16; ++i) Sh[i] = (u32)__shfl_xor((int)Qk[i], 32);

        // B-frags: frag ks keys = 16ks+8lq+j ; quadA from lq'=0, quadB from lq'=1
        bf16x8 pf[4];
        #pragma unroll
        for (int ks = 0; ks < 4; ++ks) {
            int z = 2 * ks + lq, base = (z >> 2) * 8 + (z & 3) * 2;
            u32x4 w;
            if (lq == 0) { w[0] = Qk[base]; w[1] = Qk[base + 1]; w[2] = Sh[base]; w[3] = Sh[base + 1]; }
            else         { w[0] = Sh[base]; w[1] = Sh[base + 1]; w[2] = Qk[base]; w[3] = Qk[base + 1]; }
            pf[ks] = __builtin_bit_cast(bf16x8, w);
        }

        // O^T += V^T * P
        #pragma unroll
        for (int ct = 0; ct < 4; ++ct) {
            #pragma unroll
            for (int ks = 0; ks < 4; ++ks) {
                bf16x8 va = *(const bf16x8*)&vT[half][p][ct * 32 + lr][ks * 16 + lq * 8];
                acc[ct] = mfma32(va, pf[ks], acc[ct]);
            }
        }

        // stage chunk it+1 (in regs) into the other buffer; prefetch it+2
        storeV(1 - p, vr);
        if (it + 2 < 32) loadV(it + 2, vr);
        __syncthreads();
    }

    // ---- merge halves (exact, fp32) ----
    float* mrg = (float*)&vT[0][0][0][0];
    float* Og  = mrg + qg * (32 * 129);          // [query][c], pitch 129: conflict-free
    float* ml  = mrg + 4 * (32 * 129) + qg * 64;

    if (half == 1) {
        if (lq == 0) { ml[lr] = m_run; ml[32 + lr] = l_run; }
        #pragma unroll
        for (int ct = 0; ct < 4; ++ct)
            #pragma unroll
            for (int r = 0; r < 16; ++r) {
                int c = (r & 3) + 8 * (r >> 2) + 4 * lq + 32 * ct;
                Og[lr * 129 + c] = acc[ct][r];
            }
    }
    __syncthreads();
    if (half == 0) {
        const float m2 = ml[lr], l2 = ml[32 + lr];
        const float mm = fmaxf(m_run, m2);
        const float e1 = __expf(m_run - mm), e2 = __expf(m2 - mm);
        const float linv = 1.0f / (e1 * l_run + e2 * l2);
        const float gg = gamma[0];
        #pragma unroll
        for (int ct = 0; ct < 4; ++ct)
            #pragma unroll
            for (int r = 0; r < 16; ++r) {
                int c = (r & 3) + 8 * (r >> 2) + 4 * lq + 32 * ct;
                size_t idx = ((size_t)(b * Cc + c)) * Nn + nq;
                out[idx] = x[idx] + gg * (e1 * acc[ct][r] + e2 * Og[lr * 129 + c]) * linv;
            }
    }
}

extern "C" void kernel_launch(void* const* d_in, const int* in_sizes, int n_in,
                              void* d_out, int out_size, void* d_ws, size_t ws_size,
                              hipStream_t stream) {
    const float* x  = (const float*)d_in[0];
    const float* Wq = (const float*)d_in[1];
    const float* Wk = (const float*)d_in[2];
    const float* Wv = (const float*)d_in[3];
    const float* gm = (const float*)d_in[4];

    float* qw = (float*)d_ws;                              // [B][N][16] fp32
    float* kw = qw + (size_t)Bb * Nn * CQ;                 // [B][N][16] fp32
    __bf16* vw = (__bf16*)(kw + (size_t)Bb * Nn * CQ);     // [B][C][N] bf16 (V^T)

    qkv_kernel<<<dim3(Nn / 64, Bb), 256, 0, stream>>>(x, Wq, Wk, Wv, qw, kw, vw);
    attn_kernel<<<dim3(Nn / 128, Bb), 512, 0, stream>>>(x, qw, kw, vw, gm,
                                                        (float*)d_out);
}